// Round 19
// baseline (137.597 us; speedup 1.0000x reference)
//
#include <hip/hip_runtime.h>

typedef __attribute__((ext_vector_type(8))) short short8;
typedef __attribute__((ext_vector_type(4))) float f32x4;
typedef __attribute__((ext_vector_type(16))) float f32x16;
typedef __attribute__((ext_vector_type(8))) int i32x8;
typedef unsigned short u16;
typedef unsigned int u32;
typedef unsigned char u8;

#define DEVFN static __device__ __forceinline__

DEVFN u16 f2b(float f) {
  u32 u = __builtin_bit_cast(u32, f);
  u32 r = u + 0x7fffu + ((u >> 16) & 1u);
  return (u16)(r >> 16);
}

DEVFN float b2f(u16 b) {
  u32 u = ((u32)b) << 16;
  return __builtin_bit_cast(float, u);
}

DEVFN short8 ldfrag(const void* p) {
  return __builtin_bit_cast(short8, *(const uint4*)p);
}

#define MFMA16(a, b, c) __builtin_amdgcn_mfma_f32_16x16x32_bf16((a), (b), (c), 0, 0, 0)
#define MFMAS(a, b, c) __builtin_amdgcn_mfma_scale_f32_32x32x64_f8f6f4((a), (b), (c), 0, 0, 0, 127, 0, 127)
#define MFMASW(a, b, c) __builtin_amdgcn_mfma_scale_f32_32x32x64_f8f6f4((a), (b), (c), 0, 0, 0, 127, 0, 123)
#define EXP2(x) __builtin_amdgcn_exp2f(x)
#define CVT8(a, b, o, hi) __builtin_amdgcn_cvt_pk_fp8_f32((a), (b), (o), (hi))
#define F8TOF(s, i) __builtin_amdgcn_cvt_f32_fp8((s), (i))

DEVFN i32x8 mk8(uint4 a, uint4 b) {
  return (i32x8){(int)a.x, (int)a.y, (int)a.z, (int)a.w, (int)b.x, (int)b.y, (int)b.z, (int)b.w};
}

DEVFN void llds16(const void* g, void* l) {
  __builtin_amdgcn_global_load_lds((const __attribute__((address_space(1))) void*)g,
                                   (__attribute__((address_space(3))) void*)l, 16, 0, 0);
}

DEVFN float gelu_exact(float v) {
  return 0.5f * v * (1.0f + erff(v * 0.70710678118654752f));
}

// sigma: swap bits 3 and 4 (involution)
DEVFN int sigma(int d) {
  return (d & ~24) | ((d & 8) << 1) | ((d & 16) >> 1);
}

// fp8 chunk-layout offset, K=256 matrices: [blk32][ks4][slot64][32B]
DEVFN size_t c8off(int row, int k) {
  return (size_t)(row >> 5) * 8192 + (k >> 6) * 2048 + ((row & 31) + 32 * ((k >> 5) & 1)) * 32 + (k & 31);
}
// fp8 chunk-layout offset, K=1024 matrices: [blk32][ks16][slot64][32B]
DEVFN size_t c8off1k(int row, int k) {
  return (size_t)(row >> 5) * 32768 + (k >> 6) * 2048 + ((row & 31) + 32 * ((k >> 5) & 1)) * 32 + (k & 31);
}

// ---------------- fused prep ----------------
__global__ __launch_bounds__(256) void k_prep(const float* Wq, const float* Wk, const float* Wv,
                                              const float* Wo, const float* W1, const float* W2,
                                              u8* Wq8, u8* Wk8, u8* Wv8,
                                              u16* Wob, u8* W18, u8* W28,
                                              const float* x, const float* g1, const float* be1,
                                              u8* h8c) {
  const int y = blockIdx.y;
  if (y < 3) {
    int i = blockIdx.x * 256 + threadIdx.x;
    if (i >= 131072) return;
    const float* s = y == 0 ? Wq : (y == 1 ? Wk : Wv);
    u8* d = y == 0 ? Wq8 : (y == 1 ? Wk8 : Wv8);
    float4 v = ((const float4*)s)[i];
    const int col = i >> 6, k = (i & 63) * 4;
    u32 q = CVT8(v.x * 16.0f, v.y * 16.0f, 0, false);
    q = CVT8(v.z * 16.0f, v.w * 16.0f, q, true);
    *(u32*)(d + c8off(col, k)) = q;
    return;
  }
  if (y == 4) {
    int i = blockIdx.x * 256 + threadIdx.x;
    if (i >= 65536) return;
    float4 v = ((const float4*)W1)[i];
    const int col = i >> 6, k = (i & 63) * 4;
    u32 q = CVT8(v.x * 16.0f, v.y * 16.0f, 0, false);
    q = CVT8(v.z * 16.0f, v.w * 16.0f, q, true);
    *(u32*)(W18 + c8off(col, k)) = q;
    return;
  }
  if (y == 5) {
    int i = blockIdx.x * 256 + threadIdx.x;
    if (i >= 65536) return;
    float4 v = ((const float4*)W2)[i];
    const int row = i >> 8, k = (i & 255) * 4;
    u32 q = CVT8(v.x * 16.0f, v.y * 16.0f, 0, false);
    q = CVT8(v.z * 16.0f, v.w * 16.0f, q, true);
    *(u32*)(W28 + c8off1k(row, k)) = q;
    return;
  }
  if (y == 3) {
    int i = blockIdx.x * 256 + threadIdx.x;
    if (i >= 131072) return;
    float4 v = ((const float4*)Wo)[i];
    ushort4 o = { f2b(v.x), f2b(v.y), f2b(v.z), f2b(v.w) };
    ((ushort4*)Wob)[i] = o;
    return;
  }
  // y==6: LayerNorm1 -> fp8 chunk
  int row = blockIdx.x * 4 + (threadIdx.x >> 6);
  int l = threadIdx.x & 63;
  const float4 v = *(const float4*)(x + (size_t)row * 256 + l * 4);
  float s = v.x + v.y + v.z + v.w;
#pragma unroll
  for (int m = 1; m < 64; m <<= 1) s += __shfl_xor(s, m);
  float mu = s * (1.0f / 256.0f);
  float dx = v.x - mu, dy = v.y - mu, dz = v.z - mu, dw = v.w - mu;
  float q = dx * dx + dy * dy + dz * dz + dw * dw;
#pragma unroll
  for (int m = 1; m < 64; m <<= 1) q += __shfl_xor(q, m);
  float r = rsqrtf(q * (1.0f / 256.0f) + 1e-5f);
  float4 gv = *(const float4*)(g1 + l * 4);
  float4 bv = *(const float4*)(be1 + l * 4);
  u32 pk = CVT8(dx * r * gv.x + bv.x, dy * r * gv.y + bv.y, 0, false);
  pk = CVT8(dz * r * gv.z + bv.z, dw * r * gv.w + bv.w, pk, true);
  *(u32*)(h8c + c8off(row, l * 4)) = pk;
}

// ---------------- Wo GEMM: fp8 partial-O inputs, fused merge in A-staging -> bf16 partials ----------------
__global__ __launch_bounds__(256, 2) void k_gemm_wo(const u8* __restrict__ part,
                                                    const float* __restrict__ ml,
                                                    const u16* __restrict__ B,
                                                    u16* __restrict__ out) {
  constexpr int M = 4096, N = 256, K = 2048;
  __shared__ __attribute__((aligned(16))) u16 As[128 * 32];
  __shared__ __attribute__((aligned(16))) u16 Bs[128 * 32];
  const int t = threadIdx.x;
  const int w = t >> 6, l = t & 63, g = l >> 4, c = l & 15;
  const int wr = w >> 1, wc = w & 1;
  const int bm = blockIdx.y, bn = blockIdx.x;
  const int kk0 = blockIdx.z * 16;
  const int h0 = kk0 >> 3;

  // A-staging: one row per thread-pair
  const int arow = t >> 1;        // 0..127
  const int aj = t & 1;           // 16-byte (16-k) slot
  const int ra = bm * 128 + arow;
  // B-staging indices (bf16, unchanged)
  const int srow = t >> 2;
  const int sj = t & 3;

  float wgtA[2];
#pragma unroll
  for (int hh = 0; hh < 2; ++hh) {
    const int h = h0 + hh;
    float l0 = ml[(0 + h) * 4096 + ra];
    float l1 = ml[(8 + h) * 4096 + ra];
    wgtA[hh] = 1.0f / (l0 + l1);
  }

  f32x4 acc[4][4] = {};
  const size_t PSTRIDE8 = (size_t)4096 * 2048;
  const char* Bbase = (const char*)B;

  for (int kk = kk0; kk < kk0 + 16; ++kk) {
    const int hh = (kk >> 3) & 1;
    const float wA = wgtA[hh];
    const u8* pA = part + (size_t)ra * 2048 + kk * 32 + aj * 16;
    uint4 q0 = *(const uint4*)pA;
    uint4 q1 = *(const uint4*)(pA + PSTRIDE8);
    uint4 b0 = *(const uint4*)(Bbase + ((size_t)(bn * 128 + srow) * K) * 2 + (size_t)kk * 64 + sj * 16);
    uint4 b1 = *(const uint4*)(Bbase + ((size_t)(bn * 128 + srow + 64) * K) * 2 + (size_t)kk * 64 + sj * 16);

    // merge: bf16 = (fp8a + fp8b) * wA, packed via cvt_pk_bf16
    u32 aw[8];
    const u32* s0 = (const u32*)&q0;
    const u32* s1 = (const u32*)&q1;
#pragma unroll
    for (int wd = 0; wd < 4; ++wd) {
      float m0 = (F8TOF(s0[wd], 0) + F8TOF(s1[wd], 0)) * wA;
      float m1 = (F8TOF(s0[wd], 1) + F8TOF(s1[wd], 1)) * wA;
      float m2 = (F8TOF(s0[wd], 2) + F8TOF(s1[wd], 2)) * wA;
      float m3 = (F8TOF(s0[wd], 3) + F8TOF(s1[wd], 3)) * wA;
      u32 lo, hi;
      asm("v_cvt_pk_bf16_f32 %0, %1, %2" : "=v"(lo) : "v"(m0), "v"(m1));
      asm("v_cvt_pk_bf16_f32 %0, %1, %2" : "=v"(hi) : "v"(m2), "v"(m3));
      aw[wd * 2] = lo;
      aw[wd * 2 + 1] = hi;
    }

    __syncthreads();
    const int swA = ((arow >> 1) & 3) << 4;
    uint4 aw0 = { aw[0], aw[1], aw[2], aw[3] };
    uint4 aw1 = { aw[4], aw[5], aw[6], aw[7] };
    *(uint4*)((char*)As + arow * 64 + ((aj * 32) ^ swA)) = aw0;
    *(uint4*)((char*)As + arow * 64 + ((aj * 32 + 16) ^ swA)) = aw1;
    const int sw0 = (sj * 16) ^ (((srow >> 1) & 3) << 4);
    const int sw1 = (sj * 16) ^ ((((srow + 64) >> 1) & 3) << 4);
    *(uint4*)((char*)Bs + srow * 64 + sw0) = b0;
    *(uint4*)((char*)Bs + (srow + 64) * 64 + sw1) = b1;
    __syncthreads();
    short8 af[4], bfr[4];
#pragma unroll
    for (int m = 0; m < 4; ++m) {
      int row = wr * 64 + m * 16 + c;
      af[m] = ldfrag((const char*)As + row * 64 + ((g * 16) ^ (((row >> 1) & 3) << 4)));
    }
#pragma unroll
    for (int n = 0; n < 4; ++n) {
      int row = wc * 64 + n * 16 + c;
      bfr[n] = ldfrag((const char*)Bs + row * 64 + ((g * 16) ^ (((row >> 1) & 3) << 4)));
    }
#pragma unroll
    for (int m = 0; m < 4; ++m)
#pragma unroll
      for (int n = 0; n < 4; ++n) acc[m][n] = MFMA16(af[m], bfr[n], acc[m][n]);
  }

  const int row0 = bm * 128 + wr * 64 + 4 * g;
  const int col0 = bn * 128 + wc * 64 + c;
  u16* po = out + (size_t)blockIdx.z * M * N;
#pragma unroll
  for (int m = 0; m < 4; ++m)
#pragma unroll
    for (int n = 0; n < 4; ++n)
#pragma unroll
      for (int rr = 0; rr < 4; ++rr)
        po[(size_t)(row0 + m * 16 + rr) * N + col0 + n * 16] = f2b(acc[m][n][rr]);
}

// ---------------- MX QKV GEMM ----------------
__global__ __launch_bounds__(256, 2) void k_gemm_qkv(const u8* __restrict__ h8c,
                                                     const u8* __restrict__ Wq8,
                                                     const u8* __restrict__ Wk8,
                                                     const u8* __restrict__ Wv8,
                                                     u8* __restrict__ Oq,
                                                     u8* __restrict__ Ok,
                                                     u8* __restrict__ Ov8) {
  __shared__ __attribute__((aligned(16))) char As[32768];
  __shared__ __attribute__((aligned(16))) char Bs[32768];
  const int t = threadIdx.x;
  const int w = t >> 6, l = t & 63;
  const int q31 = l & 31, hi = l >> 5;
  const int wr = w >> 1, wc = w & 1;
  const int sel = blockIdx.x >> 4;
  const int bn = blockIdx.x & 15;
  const int bm = blockIdx.y;
  const u8* B = sel == 0 ? Wq8 : (sel == 1 ? Wk8 : Wv8);

#pragma unroll
  for (int ii = 0; ii < 8; ++ii) {
    const int inst = w * 8 + ii;
    llds16(h8c + (size_t)bm * 32768 + inst * 1024 + l * 16, As + inst * 1024);
  }
#pragma unroll
  for (int ii = 0; ii < 8; ++ii) {
    const int inst = w * 8 + ii;
    llds16(B + (size_t)bn * 32768 + inst * 1024 + l * 16, Bs + inst * 1024);
  }
  asm volatile("s_waitcnt vmcnt(0)" ::: "memory");
  __builtin_amdgcn_s_barrier();

  f32x16 acc[2][2] = {};
#pragma unroll
  for (int ks = 0; ks < 4; ++ks) {
    i32x8 af[2], bf8[2];
#pragma unroll
    for (int m = 0; m < 2; ++m) {
      const char* p = As + ((wr * 2 + m) * 4 + ks) * 2048 + l * 32;
      af[m] = mk8(*(const uint4*)p, *(const uint4*)(p + 16));
    }
#pragma unroll
    for (int n = 0; n < 2; ++n) {
      const char* p = Bs + ((wc * 2 + n) * 4 + ks) * 2048 + l * 32;
      bf8[n] = mk8(*(const uint4*)p, *(const uint4*)(p + 16));
    }
#pragma unroll
    for (int m = 0; m < 2; ++m)
#pragma unroll
      for (int n = 0; n < 2; ++n) acc[m][n] = MFMASW(af[m], bf8[n], acc[m][n]);
  }

#pragma unroll
  for (int m = 0; m < 2; ++m) {
#pragma unroll
    for (int n = 0; n < 2; ++n) {
      const int col = bn * 128 + wc * 64 + n * 32 + q31;
      const int rbase = bm * 128 + wr * 64 + m * 32 + 4 * hi;
      const int d = col & 255, h = col >> 8;
#pragma unroll
      for (int j = 0; j < 4; ++j) {
        const int kv0 = rbase + 8 * j;
        u32 q = CVT8(acc[m][n][4 * j], acc[m][n][4 * j + 1], 0, false);
        q = CVT8(acc[m][n][4 * j + 2], acc[m][n][4 * j + 3], q, true);
        if (sel == 0) {
#pragma unroll
          for (int e = 0; e < 4; ++e)
            Oq[(size_t)(kv0 + e) * 2048 + col] = (u8)(q >> (8 * e));
        } else if (sel == 1) {
#pragma unroll
          for (int e = 0; e < 4; ++e) {
            const int kv = kv0 + e;
            Ok[(size_t)h * 1048576 + (size_t)(kv >> 5) * 8192 + (d >> 6) * 2048 +
               (((d & 31) >> 4)) * 1024 + ((kv & 31) + 32 * ((d >> 5) & 1)) * 16 + (d & 15)] =
                (u8)(q >> (8 * e));
          }
        } else {
          const int s = sigma(kv0 & 31);
          *(u32*)(Ov8 + (size_t)h * 1048576 + (size_t)(kv0 >> 6) * 16384 + (d >> 5) * 2048 +
                  ((kv0 >> 5) & 1) * 1024 + ((d & 31) + 32 * (s >> 4)) * 16 + (s & 15)) = q;
        }
      }
    }
  }
}

// ---------------- MX FFN1 -> GELU -> fp8 chunk1k ----------------
__global__ __launch_bounds__(256, 2) void k_gemm_ffn1(const u8* __restrict__ A8,
                                                      const u8* __restrict__ B8,
                                                      const float* __restrict__ bias,
                                                      u8* __restrict__ out8) {
  __shared__ __attribute__((aligned(16))) char As[32768];
  __shared__ __attribute__((aligned(16))) char Bs[32768];
  const int t = threadIdx.x;
  const int w = t >> 6, l = t & 63;
  const int q31 = l & 31, hi = l >> 5;
  const int wr = w >> 1, wc = w & 1;
  const int bn = blockIdx.x;
  const int bm = blockIdx.y;

#pragma unroll
  for (int ii = 0; ii < 8; ++ii) {
    const int inst = w * 8 + ii;
    llds16(A8 + (size_t)bm * 32768 + inst * 1024 + l * 16, As + inst * 1024);
  }
#pragma unroll
  for (int ii = 0; ii < 8; ++ii) {
    const int inst = w * 8 + ii;
    llds16(B8 + (size_t)bn * 32768 + inst * 1024 + l * 16, Bs + inst * 1024);
  }
  asm volatile("s_waitcnt vmcnt(0)" ::: "memory");
  __builtin_amdgcn_s_barrier();

  f32x16 acc[2][2] = {};
#pragma unroll
  for (int ks = 0; ks < 4; ++ks) {
    i32x8 af[2], bf8[2];
#pragma unroll
    for (int m = 0; m < 2; ++m) {
      const char* p = As + ((wr * 2 + m) * 4 + ks) * 2048 + l * 32;
      af[m] = mk8(*(const uint4*)p, *(const uint4*)(p + 16));
    }
#pragma unroll
    for (int n = 0; n < 2; ++n) {
      const char* p = Bs + ((wc * 2 + n) * 4 + ks) * 2048 + l * 32;
      bf8[n] = mk8(*(const uint4*)p, *(const uint4*)(p + 16));
    }
#pragma unroll
    for (int m = 0; m < 2; ++m)
#pragma unroll
      for (int n = 0; n < 2; ++n) acc[m][n] = MFMASW(af[m], bf8[n], acc[m][n]);
  }

#pragma unroll
  for (int m = 0; m < 2; ++m) {
#pragma unroll
    for (int n = 0; n < 2; ++n) {
      const int col = bn * 128 + wc * 64 + n * 32 + q31;
      const int rbase = bm * 128 + wr * 64 + m * 32 + 4 * hi;
      const float bc = bias[col];
      const size_t base = (size_t)(rbase >> 5) * 32768 + (col >> 6) * 2048 +
                          32 * ((col >> 5) & 1) * 32 + (col & 31);
#pragma unroll
      for (int j = 0; j < 4; ++j) {
        const int rl = (rbase & 31) + 8 * j;
#pragma unroll
        for (int e = 0; e < 4; ++e)
          out8[base + (size_t)(rl + e) * 32] =
              (u8)(CVT8(gelu_exact(acc[m][n][4 * j + e] + bc), 0.0f, 0, false) & 0xff);
      }
    }
  }
}

// ---------------- MX FFN2 -> bf16 partials ----------------
__global__ __launch_bounds__(256, 2) void k_gemm_ffn2(const u8* __restrict__ A8,
                                                      const u8* __restrict__ B8,
                                                      u16* __restrict__ out) {
  __shared__ __attribute__((aligned(16))) char As[32768];
  __shared__ __attribute__((aligned(16))) char Bs[32768];
  const int t = threadIdx.x;
  const int w = t >> 6, l = t & 63;
  const int q31 = l & 31, hi = l >> 5;
  const int wr = w >> 1, wc = w & 1;
  const int bn = blockIdx.x;
  const int bm = blockIdx.y;
  const int z = blockIdx.z;

#pragma unroll
  for (int ii = 0; ii < 8; ++ii) {
    const int inst = w * 8 + ii;
    llds16(A8 + (size_t)(bm * 4 + (inst >> 3)) * 32768 + z * 8192 + (inst & 7) * 1024 + l * 16,
           As + inst * 1024);
  }
#pragma unroll
  for (int ii = 0; ii < 8; ++ii) {
    const int inst = w * 8 + ii;
    llds16(B8 + (size_t)(bn * 4 + (inst >> 3)) * 32768 + z * 8192 + (inst & 7) * 1024 + l * 16,
           Bs + inst * 1024);
  }
  asm volatile("s_waitcnt vmcnt(0)" ::: "memory");
  __builtin_amdgcn_s_barrier();

  f32x16 acc[2][2] = {};
#pragma unroll
  for (int ks = 0; ks < 4; ++ks) {
    i32x8 af[2], bf8[2];
#pragma unroll
    for (int m = 0; m < 2; ++m) {
      const char* p = As + ((wr * 2 + m) * 4 + ks) * 2048 + l * 32;
      af[m] = mk8(*(const uint4*)p, *(const uint4*)(p + 16));
    }
#pragma unroll
    for (int n = 0; n < 2; ++n) {
      const char* p = Bs + ((wc * 2 + n) * 4 + ks) * 2048 + l * 32;
      bf8[n] = mk8(*(const uint4*)p, *(const uint4*)(p + 16));
    }
#pragma unroll
    for (int m = 0; m < 2; ++m)
#pragma unroll
      for (int n = 0; n < 2; ++n) acc[m][n] = MFMASW(af[m], bf8[n], acc[m][n]);
  }

  u16* po = out + (size_t)z * 4096 * 256;
#pragma unroll
  for (int m = 0; m < 2; ++m) {
#pragma unroll
    for (int n = 0; n < 2; ++n) {
      const int col = bn * 128 + wc * 64 + n * 32 + q31;
      const int rbase = bm * 128 + wr * 64 + m * 32 + 4 * hi;
#pragma unroll
      for (int j = 0; j < 4; ++j) {
        const int r0j = rbase + 8 * j;
#pragma unroll
        for (int e = 0; e < 4; ++e)
          po[(size_t)(r0j + e) * 256 + col] = f2b(acc[m][n][4 * j + e]);
      }
    }
  }
}

// ---------------- reduce 4 bf16 partials + bias + residual -> f32 ----------------
__global__ __launch_bounds__(256) void k_red4(const u16* __restrict__ p,
                                              const float* __restrict__ bias,
                                              const float* __restrict__ resid,
                                              float* __restrict__ out) {
  int i = blockIdx.x * 256 + threadIdx.x;
  ushort4 a = *(const ushort4*)(p + (size_t)i * 4);
  ushort4 b = *(const ushort4*)(p + 1048576 * 1 + (size_t)i * 4);
  ushort4 c = *(const ushort4*)(p + 1048576 * 2 + (size_t)i * 4);
  ushort4 d = *(const ushort4*)(p + 1048576 * 3 + (size_t)i * 4);
  float4 r = ((const float4*)resid)[i];
  float4 bb = ((const float4*)bias)[i & 63];
  float4 o;
  o.x = b2f(a.x) + b2f(b.x) + b2f(c.x) + b2f(d.x) + r.x + bb.x;
  o.y = b2f(a.y) + b2f(b.y) + b2f(c.y) + b2f(d.y) + r.y + bb.y;
  o.z = b2f(a.z) + b2f(b.z) + b2f(c.z) + b2f(d.z) + r.z + bb.z;
  o.w = b2f(a.w) + b2f(b.w) + b2f(c.w) + b2f(d.w) + r.w + bb.w;
  ((float4*)out)[i] = o;
}

// ---------------- fused: reduce + LN2 -> fp8 chunk ----------------
__global__ __launch_bounds__(256) void k_red4ln(const u16* __restrict__ p,
                                                const float* __restrict__ bias,
                                                const float* __restrict__ resid,
                                                const float* __restrict__ g,
                                                const float* __restrict__ b,
                                                float* __restrict__ x2,
                                                u8* __restrict__ h28) {
  int row = blockIdx.x * 4 + (threadIdx.x >> 6);
  int l = threadIdx.x & 63;
  int i = row * 64 + l;
  ushort4 a = *(const ushort4*)(p + (size_t)i * 4);
  ushort4 bq = *(const ushort4*)(p + 1048576 * 1 + (size_t)i * 4);
  ushort4 cq = *(const ushort4*)(p + 1048576 * 2 + (size_t)i * 4);
  ushort4 dq = *(const ushort4*)(p + 1048576 * 3 + (size_t)i * 4);
  float4 r = ((const float4*)resid)[i];
  float4 bi = ((const float4*)bias)[l];
  float4 v;
  v.x = b2f(a.x) + b2f(bq.x) + b2f(cq.x) + b2f(dq.x) + r.x + bi.x;
  v.y = b2f(a.y) + b2f(bq.y) + b2f(cq.y) + b2f(dq.y) + r.y + bi.y;
  v.z = b2f(a.z) + b2f(bq.z) + b2f(cq.z) + b2f(dq.z) + r.z + bi.z;
  v.w = b2f(a.w) + b2f(bq.w) + b2f(cq.w) + b2f(dq.w) + r.w + bi.w;
  ((float4*)x2)[i] = v;
  float s = v.x + v.y + v.z + v.w;
#pragma unroll
  for (int m = 1; m < 64; m <<= 1) s += __shfl_xor(s, m);
  float mu = s * (1.0f / 256.0f);
  float dx = v.x - mu, dy = v.y - mu, dz = v.z - mu, dw = v.w - mu;
  float q = dx * dx + dy * dy + dz * dz + dw * dw;
#pragma unroll
  for (int m = 1; m < 64; m <<= 1) q += __shfl_xor(q, m);
  float rr = rsqrtf(q * (1.0f / 256.0f) + 1e-5f);
  float4 gv = *(const float4*)(g + l * 4);
  float4 bv = *(const float4*)(b + l * 4);
  u32 pk = CVT8(dx * rr * gv.x + bv.x, dy * rr * gv.y + bv.y, 0, false);
  pk = CVT8(dz * rr * gv.z + bv.z, dw * rr * gv.w + bv.w, pk, true);
  *(u32*)(h28 + c8off(row, l * 4)) = pk;
}

// ---------------- Flash attention (kv-split-2), MX-scaled fp8 K=64, fp8 partial-O out ----------------
__global__ __launch_bounds__(256, 2) void k_attn(const u8* __restrict__ Q8,
                                                 const u8* __restrict__ K8,
                                                 const u8* __restrict__ V8,
                                                 u8* __restrict__ part,
                                                 float* __restrict__ ml) {
  __shared__ __attribute__((aligned(16))) char smem[49152];
  const int t = threadIdx.x;
  const int w = t >> 6, l = t & 63;
  const int q31 = l & 31, hi = l >> 5;
  const int head = blockIdx.x, qb = blockIdx.y, sp = blockIdx.z;
  const int cbase = sp * 64;
  const float C2 = 0.0625f * 1.44269504f;
  const float MC = 16.0f * C2;

  i32x8 qv[4];
  {
    const u8* qp = Q8 + (size_t)(qb * 128 + w * 32 + q31) * 2048 + head * 256 + hi * 32;
#pragma unroll
    for (int m = 0; m < 4; ++m)
      qv[m] = mk8(*(const uint4*)(qp + m * 64), *(const uint4*)(qp + m * 64 + 16));
  }

  f32x16 o[8] = {};
  float lsum = 0.0f;

  const u8* Kc = K8 + (size_t)head * 1048576;
  const u8* Vc = V8 + (size_t)head * 1048576;

  auto stageK = [&](int cc) {
    char* kd = smem + (cc & 1) * 8192;
    const u8* src = Kc + (size_t)(cbase + cc) * 8192;
#pragma unroll
    for (int ii = 0; ii < 2; ++ii) {
      const int inst = w * 2 + ii;
      llds16(src + inst * 1024 + l * 16, kd + inst * 1024);
    }
  };
  auto stageV = [&](int pp) {
    char* vd = smem + 16384 + (pp & 1) * 16384;
    const u8* src = Vc + (size_t)(sp * 32 + pp) * 16384;
#pragma unroll
    for (int ii = 0; ii < 4; ++ii) {
      const int inst = w * 4 + ii;
      llds16(src + inst * 1024 + l * 16, vd + inst * 1024);
    }
  };

  auto qkchunk = [&](int c, u32 pq[4]) {
    const char* kd = smem + (c & 1) * 8192;
    f32x16 s = {};
    __builtin_amdgcn_s_setprio(1);
#pragma unroll
    for (int m = 0; m < 4; ++m) {
      uint4 k0 = *(const uint4*)(kd + m * 2048 + l * 16);
      uint4 k1 = *(const uint4*)(kd + m * 2048 + 1024 + l * 16);
      s = MFMAS(mk8(k0, k1), qv[m], s);
    }
    __builtin_amdgcn_s_setprio(0);
    float p[16];
#pragma unroll
    for (int i = 0; i < 16; ++i) p[i] = EXP2(fmaf(s[i], C2, -MC));
    float r8[8];
#pragma unroll
    for (int i = 0; i < 8; ++i) r8[i] = p[i] + p[i + 8];
#pragma unroll
    for (int i = 0; i < 4; ++i) r8[i] += r8[i + 4];
    float rs = (r8[0] + r8[1]) + (r8[2] + r8[3]);
    rs += __shfl_xor(rs, 32);
    lsum += rs;
    u32 a0 = CVT8(p[0], p[1], 0, false);
    a0 = CVT8(p[2], p[3], a0, true);
    u32 a1 = CVT8(p[4], p[5], 0, false);
    a1 = CVT8(p[6], p[7], a1, true);
    u32 a2 = CVT8(p[8], p[9], 0, false);
    a2 = CVT8(p[10], p[11], a2, true);
    u32 a3 = CVT8(p[12], p[13], 0, false);
    a3 = CVT8(p[14], p[15], a3, true);
    asm("v_permlane32_swap_b32 %0, %1" : "+v"(a0), "+v"(a1));
    asm("v_permlane32_swap_b32 %0, %1" : "+v"(a2), "+v"(a3));
    pq[0] = a0; pq[1] = a1; pq[2] = a2; pq[3] = a3;
  };

  stageK(0);
  stageV(0);
  for (int cp = 0; cp < 32; ++cp) {
    const int c0 = 2 * cp;
    asm volatile("s_waitcnt vmcnt(4)" ::: "memory");
    __builtin_amdgcn_s_barrier();
    __builtin_amdgcn_sched_barrier(0);
    stageK(c0 + 1);
    u32 pe[4];
    qkchunk(c0, pe);

    asm volatile("s_waitcnt vmcnt(0)" ::: "memory");
    __builtin_amdgcn_s_barrier();
    __builtin_amdgcn_sched_barrier(0);
    if (cp < 31) {
      stageK(c0 + 2);
      stageV(cp + 1);
    }
    u32 po[4];
    qkchunk(c0 + 1, po);

    i32x8 a8 = {(int)pe[0], (int)pe[1], (int)pe[2], (int)pe[3],
                (int)po[0], (int)po[1], (int)po[2], (int)po[3]};
    const char* vd = smem + 16384 + (cp & 1) * 16384;
    __builtin_amdgcn_s_setprio(1);
#pragma unroll
    for (int dt = 0; dt < 8; ++dt) {
      uint4 v0 = *(const uint4*)(vd + dt * 2048 + l * 16);
      uint4 v1 = *(const uint4*)(vd + dt * 2048 + 1024 + l * 16);
      o[dt] = MFMAS(a8, mk8(v0, v1), o[dt]);
    }
    __builtin_amdgcn_s_setprio(0);
  }

  // epilogue: unnormalized fp8 partial-O + lsum
  u8* pb = part + (size_t)sp * 4096 * 2048;
#pragma unroll
  for (int i = 0; i < 16; ++i) {
    const int r = (i & 3) + 8 * (i >> 2) + 4 * hi;
    const size_t qg = (size_t)(qb * 128 + w * 32 + r);
#pragma unroll
    for (int dt = 0; dt < 8; ++dt)
      pb[qg * 2048 + head * 256 + dt * 32 + q31] =
          (u8)(CVT8(o[dt][i], 0.0f, 0, false) & 0xff);
  }
  if (hi == 0) {
    const int qg = qb * 128 + w * 32 + q31;
    ml[(sp * 8 + head) * 4096 + qg] = lsum;
  }
}

// ---------------- launch ----------------
extern "C" void kernel_launch(void* const* d_in, const int* in_sizes, int n_in,
                              void* d_out, int out_size, void* d_ws, size_t ws_size,
                              hipStream_t stream) {
  const float* x   = (const float*)d_in[0];
  const float* Wq  = (const float*)d_in[1];
  const float* Wk  = (const float*)d_in[2];
  const float* Wv  = (const float*)d_in[3];
  const float* Wo  = (const float*)d_in[4];
  const float* bo  = (const float*)d_in[5];
  const float* g1  = (const float*)d_in[6];
  const float* be1 = (const float*)d_in[7];
  const float* g2  = (const float*)d_in[8];
  const float* be2 = (const float*)d_in[9];
  const float* W1  = (const float*)d_in[10];
  const float* b1  = (const float*)d_in[11];
  const float* W2  = (const float*)d_in[12];
  const float* b2  = (const float*)d_in[13];

  char* ws = (char*)d_ws;
  size_t off = 0;
  auto alloc = [&](size_t n) {
    char* p = ws + off;
    off = (off + n + 255) & ~(size_t)255;
    return p;
  };
  u8*  h8c   = (u8*)alloc(4096 * 256);
  u8*  Wq8   = (u8*)alloc(2048 * 256);
  u8*  Wk8   = (u8*)alloc(2048 * 256);
  u8*  Wv8   = (u8*)alloc(2048 * 256);
  u16* Wob   = (u16*)alloc(256 * 2048 * 2);
  u8*  W18   = (u8*)alloc(1024 * 256);
  u8*  W28   = (u8*)alloc(256 * 1024);
  u8*  Qb8   = (u8*)alloc((size_t)4096 * 2048);
  u8*  Kb8   = (u8*)alloc((size_t)4096 * 2048);
  u8*  Vb8   = (u8*)alloc((size_t)2048 * 4096);
  u8*  attnb = (u8*)alloc((size_t)2 * 4096 * 2048);   // fp8 partial-O x2
  float* mlb = (float*)alloc(16 * 4096 * 4);
  float* x2  = (float*)alloc(4096 * 256 * 4);
  u8*  h28   = (u8*)alloc(4096 * 256);
  u8*  ffn18 = (u8*)alloc((size_t)4096 * 1024);
  u16* pbuf  = (u16*)Qb8;  // 8MB: 4x [4096][256] bf16 partials (Qb8 dead after attn)

  k_prep<<<dim3(1024, 7), 256, 0, stream>>>(Wq, Wk, Wv, Wo, W1, W2,
                                            Wq8, Wk8, Wv8, Wob, W18, W28,
                                            x, g1, be1, h8c);

  k_gemm_qkv<<<dim3(48, 32), 256, 0, stream>>>(h8c, Wq8, Wk8, Wv8, Qb8, Kb8, Vb8);

  k_attn<<<dim3(8, 32, 2), 256, 0, stream>>>(Qb8, Kb8, Vb8, attnb, mlb);

  k_gemm_wo<<<dim3(2, 32, 4), 256, 0, stream>>>(attnb, mlb, Wob, pbuf);
  k_red4ln<<<1024, 256, 0, stream>>>(pbuf, bo, x, g2, be2, x2, h28);
  k_gemm_ffn1<<<dim3(8, 32), 256, 0, stream>>>(h28, W18, b1, ffn18);
  k_gemm_ffn2<<<dim3(2, 32, 4), 256, 0, stream>>>(ffn18, W28, pbuf);
  k_red4<<<1024, 256, 0, stream>>>(pbuf, b2, x2, (float*)d_out);
}

// Round 20
// 136.703 us; speedup vs baseline: 1.0065x; 1.0065x over previous
//
#include <hip/hip_runtime.h>

typedef __attribute__((ext_vector_type(8))) short short8;
typedef __attribute__((ext_vector_type(4))) float f32x4;
typedef __attribute__((ext_vector_type(16))) float f32x16;
typedef __attribute__((ext_vector_type(8))) int i32x8;
typedef unsigned short u16;
typedef unsigned int u32;
typedef unsigned char u8;

#define DEVFN static __device__ __forceinline__

DEVFN u16 f2b(float f) {
  u32 u = __builtin_bit_cast(u32, f);
  u32 r = u + 0x7fffu + ((u >> 16) & 1u);
  return (u16)(r >> 16);
}

DEVFN float b2f(u16 b) {
  u32 u = ((u32)b) << 16;
  return __builtin_bit_cast(float, u);
}

DEVFN short8 ldfrag(const void* p) {
  return __builtin_bit_cast(short8, *(const uint4*)p);
}

#define MFMA16(a, b, c) __builtin_amdgcn_mfma_f32_16x16x32_bf16((a), (b), (c), 0, 0, 0)
#define MFMAS(a, b, c) __builtin_amdgcn_mfma_scale_f32_32x32x64_f8f6f4((a), (b), (c), 0, 0, 0, 127, 0, 127)
#define MFMASW(a, b, c) __builtin_amdgcn_mfma_scale_f32_32x32x64_f8f6f4((a), (b), (c), 0, 0, 0, 127, 0, 123)
#define EXP2(x) __builtin_amdgcn_exp2f(x)
#define CVT8(a, b, o, hi) __builtin_amdgcn_cvt_pk_fp8_f32((a), (b), (o), (hi))
#define F8TOF(s, i) __builtin_amdgcn_cvt_f32_fp8((s), (i))

DEVFN i32x8 mk8(uint4 a, uint4 b) {
  return (i32x8){(int)a.x, (int)a.y, (int)a.z, (int)a.w, (int)b.x, (int)b.y, (int)b.z, (int)b.w};
}

DEVFN void llds16(const void* g, void* l) {
  __builtin_amdgcn_global_load_lds((const __attribute__((address_space(1))) void*)g,
                                   (__attribute__((address_space(3))) void*)l, 16, 0, 0);
}

DEVFN float gelu_exact(float v) {
  return 0.5f * v * (1.0f + erff(v * 0.70710678118654752f));
}

// sigma: swap bits 3 and 4 (involution)
DEVFN int sigma(int d) {
  return (d & ~24) | ((d & 8) << 1) | ((d & 16) >> 1);
}

// fp8 chunk-layout offset, K=256 matrices: [blk32][ks4][slot64][32B]
DEVFN size_t c8off(int row, int k) {
  return (size_t)(row >> 5) * 8192 + (k >> 6) * 2048 + ((row & 31) + 32 * ((k >> 5) & 1)) * 32 + (k & 31);
}
// fp8 chunk-layout offset, K=1024 matrices: [blk32][ks16][slot64][32B]
DEVFN size_t c8off1k(int row, int k) {
  return (size_t)(row >> 5) * 32768 + (k >> 6) * 2048 + ((row & 31) + 32 * ((k >> 5) & 1)) * 32 + (k & 31);
}

// ---------------- fused prep ----------------
__global__ __launch_bounds__(256) void k_prep(const float* Wq, const float* Wk, const float* Wv,
                                              const float* Wo, const float* W1, const float* W2,
                                              u8* Wq8, u8* Wk8, u8* Wv8,
                                              u16* Wob, u8* W18, u8* W28,
                                              const float* x, const float* g1, const float* be1,
                                              u8* h8c) {
  const int y = blockIdx.y;
  if (y < 3) {
    int i = blockIdx.x * 256 + threadIdx.x;
    if (i >= 131072) return;
    const float* s = y == 0 ? Wq : (y == 1 ? Wk : Wv);
    u8* d = y == 0 ? Wq8 : (y == 1 ? Wk8 : Wv8);
    float4 v = ((const float4*)s)[i];
    const int col = i >> 6, k = (i & 63) * 4;
    u32 q = CVT8(v.x * 16.0f, v.y * 16.0f, 0, false);
    q = CVT8(v.z * 16.0f, v.w * 16.0f, q, true);
    *(u32*)(d + c8off(col, k)) = q;
    return;
  }
  if (y == 4) {
    int i = blockIdx.x * 256 + threadIdx.x;
    if (i >= 65536) return;
    float4 v = ((const float4*)W1)[i];
    const int col = i >> 6, k = (i & 63) * 4;
    u32 q = CVT8(v.x * 16.0f, v.y * 16.0f, 0, false);
    q = CVT8(v.z * 16.0f, v.w * 16.0f, q, true);
    *(u32*)(W18 + c8off(col, k)) = q;
    return;
  }
  if (y == 5) {
    int i = blockIdx.x * 256 + threadIdx.x;
    if (i >= 65536) return;
    float4 v = ((const float4*)W2)[i];
    const int row = i >> 8, k = (i & 255) * 4;
    u32 q = CVT8(v.x * 16.0f, v.y * 16.0f, 0, false);
    q = CVT8(v.z * 16.0f, v.w * 16.0f, q, true);
    *(u32*)(W28 + c8off1k(row, k)) = q;
    return;
  }
  if (y == 3) {
    int i = blockIdx.x * 256 + threadIdx.x;
    if (i >= 131072) return;
    float4 v = ((const float4*)Wo)[i];
    ushort4 o = { f2b(v.x), f2b(v.y), f2b(v.z), f2b(v.w) };
    ((ushort4*)Wob)[i] = o;
    return;
  }
  // y==6: LayerNorm1 -> fp8 chunk
  int row = blockIdx.x * 4 + (threadIdx.x >> 6);
  int l = threadIdx.x & 63;
  const float4 v = *(const float4*)(x + (size_t)row * 256 + l * 4);
  float s = v.x + v.y + v.z + v.w;
#pragma unroll
  for (int m = 1; m < 64; m <<= 1) s += __shfl_xor(s, m);
  float mu = s * (1.0f / 256.0f);
  float dx = v.x - mu, dy = v.y - mu, dz = v.z - mu, dw = v.w - mu;
  float q = dx * dx + dy * dy + dz * dz + dw * dw;
#pragma unroll
  for (int m = 1; m < 64; m <<= 1) q += __shfl_xor(q, m);
  float r = rsqrtf(q * (1.0f / 256.0f) + 1e-5f);
  float4 gv = *(const float4*)(g1 + l * 4);
  float4 bv = *(const float4*)(be1 + l * 4);
  u32 pk = CVT8(dx * r * gv.x + bv.x, dy * r * gv.y + bv.y, 0, false);
  pk = CVT8(dz * r * gv.z + bv.z, dw * r * gv.w + bv.w, pk, true);
  *(u32*)(h8c + c8off(row, l * 4)) = pk;
}

// ---------------- Wo GEMM: fp8 partial-O inputs, fused merge in A-staging -> bf16 partials ----------------
__global__ __launch_bounds__(256, 2) void k_gemm_wo(const u8* __restrict__ part,
                                                    const float* __restrict__ ml,
                                                    const u16* __restrict__ B,
                                                    u16* __restrict__ out) {
  constexpr int M = 4096, N = 256, K = 2048;
  __shared__ __attribute__((aligned(16))) u16 As[128 * 32];
  __shared__ __attribute__((aligned(16))) u16 Bs[128 * 32];
  const int t = threadIdx.x;
  const int w = t >> 6, l = t & 63, g = l >> 4, c = l & 15;
  const int wr = w >> 1, wc = w & 1;
  const int bm = blockIdx.y, bn = blockIdx.x;
  const int kk0 = blockIdx.z * 16;
  const int h0 = kk0 >> 3;

  const int arow = t >> 1;
  const int aj = t & 1;
  const int ra = bm * 128 + arow;
  const int srow = t >> 2;
  const int sj = t & 3;

  float wgtA[2];
#pragma unroll
  for (int hh = 0; hh < 2; ++hh) {
    const int h = h0 + hh;
    float l0 = ml[(0 + h) * 4096 + ra];
    float l1 = ml[(8 + h) * 4096 + ra];
    wgtA[hh] = 1.0f / (l0 + l1);
  }

  f32x4 acc[4][4] = {};
  const size_t PSTRIDE8 = (size_t)4096 * 2048;
  const char* Bbase = (const char*)B;

  for (int kk = kk0; kk < kk0 + 16; ++kk) {
    const int hh = (kk >> 3) & 1;
    const float wA = wgtA[hh];
    const u8* pA = part + (size_t)ra * 2048 + kk * 32 + aj * 16;
    uint4 q0 = *(const uint4*)pA;
    uint4 q1 = *(const uint4*)(pA + PSTRIDE8);
    uint4 b0 = *(const uint4*)(Bbase + ((size_t)(bn * 128 + srow) * K) * 2 + (size_t)kk * 64 + sj * 16);
    uint4 b1 = *(const uint4*)(Bbase + ((size_t)(bn * 128 + srow + 64) * K) * 2 + (size_t)kk * 64 + sj * 16);

    u32 aw[8];
    const u32* s0 = (const u32*)&q0;
    const u32* s1 = (const u32*)&q1;
#pragma unroll
    for (int wd = 0; wd < 4; ++wd) {
      float m0 = (F8TOF(s0[wd], 0) + F8TOF(s1[wd], 0)) * wA;
      float m1 = (F8TOF(s0[wd], 1) + F8TOF(s1[wd], 1)) * wA;
      float m2 = (F8TOF(s0[wd], 2) + F8TOF(s1[wd], 2)) * wA;
      float m3 = (F8TOF(s0[wd], 3) + F8TOF(s1[wd], 3)) * wA;
      u32 lo, hi;
      asm("v_cvt_pk_bf16_f32 %0, %1, %2" : "=v"(lo) : "v"(m0), "v"(m1));
      asm("v_cvt_pk_bf16_f32 %0, %1, %2" : "=v"(hi) : "v"(m2), "v"(m3));
      aw[wd * 2] = lo;
      aw[wd * 2 + 1] = hi;
    }

    __syncthreads();
    const int swA = ((arow >> 1) & 3) << 4;
    uint4 aw0 = { aw[0], aw[1], aw[2], aw[3] };
    uint4 aw1 = { aw[4], aw[5], aw[6], aw[7] };
    *(uint4*)((char*)As + arow * 64 + ((aj * 32) ^ swA)) = aw0;
    *(uint4*)((char*)As + arow * 64 + ((aj * 32 + 16) ^ swA)) = aw1;
    const int sw0 = (sj * 16) ^ (((srow >> 1) & 3) << 4);
    const int sw1 = (sj * 16) ^ ((((srow + 64) >> 1) & 3) << 4);
    *(uint4*)((char*)Bs + srow * 64 + sw0) = b0;
    *(uint4*)((char*)Bs + (srow + 64) * 64 + sw1) = b1;
    __syncthreads();
    short8 af[4], bfr[4];
#pragma unroll
    for (int m = 0; m < 4; ++m) {
      int row = wr * 64 + m * 16 + c;
      af[m] = ldfrag((const char*)As + row * 64 + ((g * 16) ^ (((row >> 1) & 3) << 4)));
    }
#pragma unroll
    for (int n = 0; n < 4; ++n) {
      int row = wc * 64 + n * 16 + c;
      bfr[n] = ldfrag((const char*)Bs + row * 64 + ((g * 16) ^ (((row >> 1) & 3) << 4)));
    }
#pragma unroll
    for (int m = 0; m < 4; ++m)
#pragma unroll
      for (int n = 0; n < 4; ++n) acc[m][n] = MFMA16(af[m], bfr[n], acc[m][n]);
  }

  const int row0 = bm * 128 + wr * 64 + 4 * g;
  const int col0 = bn * 128 + wc * 64 + c;
  u16* po = out + (size_t)blockIdx.z * M * N;
#pragma unroll
  for (int m = 0; m < 4; ++m)
#pragma unroll
    for (int n = 0; n < 4; ++n)
#pragma unroll
      for (int rr = 0; rr < 4; ++rr)
        po[(size_t)(row0 + m * 16 + rr) * N + col0 + n * 16] = f2b(acc[m][n][rr]);
}

// ---------------- MX QKV GEMM ----------------
__global__ __launch_bounds__(256, 2) void k_gemm_qkv(const u8* __restrict__ h8c,
                                                     const u8* __restrict__ Wq8,
                                                     const u8* __restrict__ Wk8,
                                                     const u8* __restrict__ Wv8,
                                                     u8* __restrict__ Oq,
                                                     u8* __restrict__ Ok,
                                                     u8* __restrict__ Ov8) {
  __shared__ __attribute__((aligned(16))) char As[32768];
  __shared__ __attribute__((aligned(16))) char Bs[32768];
  const int t = threadIdx.x;
  const int w = t >> 6, l = t & 63;
  const int q31 = l & 31, hi = l >> 5;
  const int wr = w >> 1, wc = w & 1;
  const int sel = blockIdx.x >> 4;
  const int bn = blockIdx.x & 15;
  const int bm = blockIdx.y;
  const u8* B = sel == 0 ? Wq8 : (sel == 1 ? Wk8 : Wv8);

#pragma unroll
  for (int ii = 0; ii < 8; ++ii) {
    const int inst = w * 8 + ii;
    llds16(h8c + (size_t)bm * 32768 + inst * 1024 + l * 16, As + inst * 1024);
  }
#pragma unroll
  for (int ii = 0; ii < 8; ++ii) {
    const int inst = w * 8 + ii;
    llds16(B + (size_t)bn * 32768 + inst * 1024 + l * 16, Bs + inst * 1024);
  }
  asm volatile("s_waitcnt vmcnt(0)" ::: "memory");
  __builtin_amdgcn_s_barrier();

  f32x16 acc[2][2] = {};
#pragma unroll
  for (int ks = 0; ks < 4; ++ks) {
    i32x8 af[2], bf8[2];
#pragma unroll
    for (int m = 0; m < 2; ++m) {
      const char* p = As + ((wr * 2 + m) * 4 + ks) * 2048 + l * 32;
      af[m] = mk8(*(const uint4*)p, *(const uint4*)(p + 16));
    }
#pragma unroll
    for (int n = 0; n < 2; ++n) {
      const char* p = Bs + ((wc * 2 + n) * 4 + ks) * 2048 + l * 32;
      bf8[n] = mk8(*(const uint4*)p, *(const uint4*)(p + 16));
    }
#pragma unroll
    for (int m = 0; m < 2; ++m)
#pragma unroll
      for (int n = 0; n < 2; ++n) acc[m][n] = MFMASW(af[m], bf8[n], acc[m][n]);
  }

#pragma unroll
  for (int m = 0; m < 2; ++m) {
#pragma unroll
    for (int n = 0; n < 2; ++n) {
      const int col = bn * 128 + wc * 64 + n * 32 + q31;
      const int rbase = bm * 128 + wr * 64 + m * 32 + 4 * hi;
      const int d = col & 255, h = col >> 8;
#pragma unroll
      for (int j = 0; j < 4; ++j) {
        const int kv0 = rbase + 8 * j;
        u32 q = CVT8(acc[m][n][4 * j], acc[m][n][4 * j + 1], 0, false);
        q = CVT8(acc[m][n][4 * j + 2], acc[m][n][4 * j + 3], q, true);
        if (sel == 0) {
#pragma unroll
          for (int e = 0; e < 4; ++e)
            Oq[(size_t)(kv0 + e) * 2048 + col] = (u8)(q >> (8 * e));
        } else if (sel == 1) {
#pragma unroll
          for (int e = 0; e < 4; ++e) {
            const int kv = kv0 + e;
            Ok[(size_t)h * 1048576 + (size_t)(kv >> 5) * 8192 + (d >> 6) * 2048 +
               (((d & 31) >> 4)) * 1024 + ((kv & 31) + 32 * ((d >> 5) & 1)) * 16 + (d & 15)] =
                (u8)(q >> (8 * e));
          }
        } else {
          const int s = sigma(kv0 & 31);
          *(u32*)(Ov8 + (size_t)h * 1048576 + (size_t)(kv0 >> 6) * 16384 + (d >> 5) * 2048 +
                  ((kv0 >> 5) & 1) * 1024 + ((d & 31) + 32 * (s >> 4)) * 16 + (s & 15)) = q;
        }
      }
    }
  }
}

// ---------------- MX FFN1 -> GELU -> fp8 chunk1k ----------------
__global__ __launch_bounds__(256, 2) void k_gemm_ffn1(const u8* __restrict__ A8,
                                                      const u8* __restrict__ B8,
                                                      const float* __restrict__ bias,
                                                      u8* __restrict__ out8) {
  __shared__ __attribute__((aligned(16))) char As[32768];
  __shared__ __attribute__((aligned(16))) char Bs[32768];
  const int t = threadIdx.x;
  const int w = t >> 6, l = t & 63;
  const int q31 = l & 31, hi = l >> 5;
  const int wr = w >> 1, wc = w & 1;
  const int bn = blockIdx.x;
  const int bm = blockIdx.y;

#pragma unroll
  for (int ii = 0; ii < 8; ++ii) {
    const int inst = w * 8 + ii;
    llds16(A8 + (size_t)bm * 32768 + inst * 1024 + l * 16, As + inst * 1024);
  }
#pragma unroll
  for (int ii = 0; ii < 8; ++ii) {
    const int inst = w * 8 + ii;
    llds16(B8 + (size_t)bn * 32768 + inst * 1024 + l * 16, Bs + inst * 1024);
  }
  asm volatile("s_waitcnt vmcnt(0)" ::: "memory");
  __builtin_amdgcn_s_barrier();

  f32x16 acc[2][2] = {};
#pragma unroll
  for (int ks = 0; ks < 4; ++ks) {
    i32x8 af[2], bf8[2];
#pragma unroll
    for (int m = 0; m < 2; ++m) {
      const char* p = As + ((wr * 2 + m) * 4 + ks) * 2048 + l * 32;
      af[m] = mk8(*(const uint4*)p, *(const uint4*)(p + 16));
    }
#pragma unroll
    for (int n = 0; n < 2; ++n) {
      const char* p = Bs + ((wc * 2 + n) * 4 + ks) * 2048 + l * 32;
      bf8[n] = mk8(*(const uint4*)p, *(const uint4*)(p + 16));
    }
#pragma unroll
    for (int m = 0; m < 2; ++m)
#pragma unroll
      for (int n = 0; n < 2; ++n) acc[m][n] = MFMASW(af[m], bf8[n], acc[m][n]);
  }

#pragma unroll
  for (int m = 0; m < 2; ++m) {
#pragma unroll
    for (int n = 0; n < 2; ++n) {
      const int col = bn * 128 + wc * 64 + n * 32 + q31;
      const int rbase = bm * 128 + wr * 64 + m * 32 + 4 * hi;
      const float bc = bias[col];
      const size_t base = (size_t)(rbase >> 5) * 32768 + (col >> 6) * 2048 +
                          32 * ((col >> 5) & 1) * 32 + (col & 31);
#pragma unroll
      for (int j = 0; j < 4; ++j) {
        const int rl = (rbase & 31) + 8 * j;
#pragma unroll
        for (int e = 0; e < 4; ++e)
          out8[base + (size_t)(rl + e) * 32] =
              (u8)(CVT8(gelu_exact(acc[m][n][4 * j + e] + bc), 0.0f, 0, false) & 0xff);
      }
    }
  }
}

// ---------------- MX FFN2 -> bf16 partials ----------------
__global__ __launch_bounds__(256, 2) void k_gemm_ffn2(const u8* __restrict__ A8,
                                                      const u8* __restrict__ B8,
                                                      u16* __restrict__ out) {
  __shared__ __attribute__((aligned(16))) char As[32768];
  __shared__ __attribute__((aligned(16))) char Bs[32768];
  const int t = threadIdx.x;
  const int w = t >> 6, l = t & 63;
  const int q31 = l & 31, hi = l >> 5;
  const int wr = w >> 1, wc = w & 1;
  const int bn = blockIdx.x;
  const int bm = blockIdx.y;
  const int z = blockIdx.z;

#pragma unroll
  for (int ii = 0; ii < 8; ++ii) {
    const int inst = w * 8 + ii;
    llds16(A8 + (size_t)(bm * 4 + (inst >> 3)) * 32768 + z * 8192 + (inst & 7) * 1024 + l * 16,
           As + inst * 1024);
  }
#pragma unroll
  for (int ii = 0; ii < 8; ++ii) {
    const int inst = w * 8 + ii;
    llds16(B8 + (size_t)(bn * 4 + (inst >> 3)) * 32768 + z * 8192 + (inst & 7) * 1024 + l * 16,
           Bs + inst * 1024);
  }
  asm volatile("s_waitcnt vmcnt(0)" ::: "memory");
  __builtin_amdgcn_s_barrier();

  f32x16 acc[2][2] = {};
#pragma unroll
  for (int ks = 0; ks < 4; ++ks) {
    i32x8 af[2], bf8[2];
#pragma unroll
    for (int m = 0; m < 2; ++m) {
      const char* p = As + ((wr * 2 + m) * 4 + ks) * 2048 + l * 32;
      af[m] = mk8(*(const uint4*)p, *(const uint4*)(p + 16));
    }
#pragma unroll
    for (int n = 0; n < 2; ++n) {
      const char* p = Bs + ((wc * 2 + n) * 4 + ks) * 2048 + l * 32;
      bf8[n] = mk8(*(const uint4*)p, *(const uint4*)(p + 16));
    }
#pragma unroll
    for (int m = 0; m < 2; ++m)
#pragma unroll
      for (int n = 0; n < 2; ++n) acc[m][n] = MFMASW(af[m], bf8[n], acc[m][n]);
  }

  u16* po = out + (size_t)z * 4096 * 256;
#pragma unroll
  for (int m = 0; m < 2; ++m) {
#pragma unroll
    for (int n = 0; n < 2; ++n) {
      const int col = bn * 128 + wc * 64 + n * 32 + q31;
      const int rbase = bm * 128 + wr * 64 + m * 32 + 4 * hi;
#pragma unroll
      for (int j = 0; j < 4; ++j) {
        const int r0j = rbase + 8 * j;
#pragma unroll
        for (int e = 0; e < 4; ++e)
          po[(size_t)(r0j + e) * 256 + col] = f2b(acc[m][n][4 * j + e]);
      }
    }
  }
}

// ---------------- reduce 4 bf16 partials + bias + residual -> f32 ----------------
__global__ __launch_bounds__(256) void k_red4(const u16* __restrict__ p,
                                              const float* __restrict__ bias,
                                              const float* __restrict__ resid,
                                              float* __restrict__ out) {
  int i = blockIdx.x * 256 + threadIdx.x;
  ushort4 a = *(const ushort4*)(p + (size_t)i * 4);
  ushort4 b = *(const ushort4*)(p + 1048576 * 1 + (size_t)i * 4);
  ushort4 c = *(const ushort4*)(p + 1048576 * 2 + (size_t)i * 4);
  ushort4 d = *(const ushort4*)(p + 1048576 * 3 + (size_t)i * 4);
  float4 r = ((const float4*)resid)[i];
  float4 bb = ((const float4*)bias)[i & 63];
  float4 o;
  o.x = b2f(a.x) + b2f(b.x) + b2f(c.x) + b2f(d.x) + r.x + bb.x;
  o.y = b2f(a.y) + b2f(b.y) + b2f(c.y) + b2f(d.y) + r.y + bb.y;
  o.z = b2f(a.z) + b2f(b.z) + b2f(c.z) + b2f(d.z) + r.z + bb.z;
  o.w = b2f(a.w) + b2f(b.w) + b2f(c.w) + b2f(d.w) + r.w + bb.w;
  ((float4*)out)[i] = o;
}

// ---------------- fused: reduce + LN2 -> fp8 chunk ----------------
__global__ __launch_bounds__(256) void k_red4ln(const u16* __restrict__ p,
                                                const float* __restrict__ bias,
                                                const float* __restrict__ resid,
                                                const float* __restrict__ g,
                                                const float* __restrict__ b,
                                                float* __restrict__ x2,
                                                u8* __restrict__ h28) {
  int row = blockIdx.x * 4 + (threadIdx.x >> 6);
  int l = threadIdx.x & 63;
  int i = row * 64 + l;
  ushort4 a = *(const ushort4*)(p + (size_t)i * 4);
  ushort4 bq = *(const ushort4*)(p + 1048576 * 1 + (size_t)i * 4);
  ushort4 cq = *(const ushort4*)(p + 1048576 * 2 + (size_t)i * 4);
  ushort4 dq = *(const ushort4*)(p + 1048576 * 3 + (size_t)i * 4);
  float4 r = ((const float4*)resid)[i];
  float4 bi = ((const float4*)bias)[l];
  float4 v;
  v.x = b2f(a.x) + b2f(bq.x) + b2f(cq.x) + b2f(dq.x) + r.x + bi.x;
  v.y = b2f(a.y) + b2f(bq.y) + b2f(cq.y) + b2f(dq.y) + r.y + bi.y;
  v.z = b2f(a.z) + b2f(bq.z) + b2f(cq.z) + b2f(dq.z) + r.z + bi.z;
  v.w = b2f(a.w) + b2f(bq.w) + b2f(cq.w) + b2f(dq.w) + r.w + bi.w;
  ((float4*)x2)[i] = v;
  float s = v.x + v.y + v.z + v.w;
#pragma unroll
  for (int m = 1; m < 64; m <<= 1) s += __shfl_xor(s, m);
  float mu = s * (1.0f / 256.0f);
  float dx = v.x - mu, dy = v.y - mu, dz = v.z - mu, dw = v.w - mu;
  float q = dx * dx + dy * dy + dz * dz + dw * dw;
#pragma unroll
  for (int m = 1; m < 64; m <<= 1) q += __shfl_xor(q, m);
  float rr = rsqrtf(q * (1.0f / 256.0f) + 1e-5f);
  float4 gv = *(const float4*)(g + l * 4);
  float4 bv = *(const float4*)(b + l * 4);
  u32 pk = CVT8(dx * rr * gv.x + bv.x, dy * rr * gv.y + bv.y, 0, false);
  pk = CVT8(dz * rr * gv.z + bv.z, dw * rr * gv.w + bv.w, pk, true);
  *(u32*)(h28 + c8off(row, l * 4)) = pk;
}

// ---------------- Flash attention (kv-split-2), MX-scaled fp8 K=64, fp8 partial-O out ----------------
// lsum xor32 hoisted out of the kv loop (linear reduction).
__global__ __launch_bounds__(256, 2) void k_attn(const u8* __restrict__ Q8,
                                                 const u8* __restrict__ K8,
                                                 const u8* __restrict__ V8,
                                                 u8* __restrict__ part,
                                                 float* __restrict__ ml) {
  __shared__ __attribute__((aligned(16))) char smem[49152];
  const int t = threadIdx.x;
  const int w = t >> 6, l = t & 63;
  const int q31 = l & 31, hi = l >> 5;
  const int head = blockIdx.x, qb = blockIdx.y, sp = blockIdx.z;
  const int cbase = sp * 64;
  const float C2 = 0.0625f * 1.44269504f;
  const float MC = 16.0f * C2;

  i32x8 qv[4];
  {
    const u8* qp = Q8 + (size_t)(qb * 128 + w * 32 + q31) * 2048 + head * 256 + hi * 32;
#pragma unroll
    for (int m = 0; m < 4; ++m)
      qv[m] = mk8(*(const uint4*)(qp + m * 64), *(const uint4*)(qp + m * 64 + 16));
  }

  f32x16 o[8] = {};
  float lsum = 0.0f;  // lane-local half-sum; xor32 applied once in epilogue

  const u8* Kc = K8 + (size_t)head * 1048576;
  const u8* Vc = V8 + (size_t)head * 1048576;

  auto stageK = [&](int cc) {
    char* kd = smem + (cc & 1) * 8192;
    const u8* src = Kc + (size_t)(cbase + cc) * 8192;
#pragma unroll
    for (int ii = 0; ii < 2; ++ii) {
      const int inst = w * 2 + ii;
      llds16(src + inst * 1024 + l * 16, kd + inst * 1024);
    }
  };
  auto stageV = [&](int pp) {
    char* vd = smem + 16384 + (pp & 1) * 16384;
    const u8* src = Vc + (size_t)(sp * 32 + pp) * 16384;
#pragma unroll
    for (int ii = 0; ii < 4; ++ii) {
      const int inst = w * 4 + ii;
      llds16(src + inst * 1024 + l * 16, vd + inst * 1024);
    }
  };

  auto qkchunk = [&](int c, u32 pq[4]) {
    const char* kd = smem + (c & 1) * 8192;
    f32x16 s = {};
    __builtin_amdgcn_s_setprio(1);
#pragma unroll
    for (int m = 0; m < 4; ++m) {
      uint4 k0 = *(const uint4*)(kd + m * 2048 + l * 16);
      uint4 k1 = *(const uint4*)(kd + m * 2048 + 1024 + l * 16);
      s = MFMAS(mk8(k0, k1), qv[m], s);
    }
    __builtin_amdgcn_s_setprio(0);
    float p[16];
#pragma unroll
    for (int i = 0; i < 16; ++i) p[i] = EXP2(fmaf(s[i], C2, -MC));
    float r8[8];
#pragma unroll
    for (int i = 0; i < 8; ++i) r8[i] = p[i] + p[i + 8];
#pragma unroll
    for (int i = 0; i < 4; ++i) r8[i] += r8[i + 4];
    lsum += (r8[0] + r8[1]) + (r8[2] + r8[3]);
    u32 a0 = CVT8(p[0], p[1], 0, false);
    a0 = CVT8(p[2], p[3], a0, true);
    u32 a1 = CVT8(p[4], p[5], 0, false);
    a1 = CVT8(p[6], p[7], a1, true);
    u32 a2 = CVT8(p[8], p[9], 0, false);
    a2 = CVT8(p[10], p[11], a2, true);
    u32 a3 = CVT8(p[12], p[13], 0, false);
    a3 = CVT8(p[14], p[15], a3, true);
    asm("v_permlane32_swap_b32 %0, %1" : "+v"(a0), "+v"(a1));
    asm("v_permlane32_swap_b32 %0, %1" : "+v"(a2), "+v"(a3));
    pq[0] = a0; pq[1] = a1; pq[2] = a2; pq[3] = a3;
  };

  stageK(0);
  stageV(0);
  for (int cp = 0; cp < 32; ++cp) {
    const int c0 = 2 * cp;
    asm volatile("s_waitcnt vmcnt(4)" ::: "memory");
    __builtin_amdgcn_s_barrier();
    __builtin_amdgcn_sched_barrier(0);
    stageK(c0 + 1);
    u32 pe[4];
    qkchunk(c0, pe);

    asm volatile("s_waitcnt vmcnt(0)" ::: "memory");
    __builtin_amdgcn_s_barrier();
    __builtin_amdgcn_sched_barrier(0);
    if (cp < 31) {
      stageK(c0 + 2);
      stageV(cp + 1);
    }
    u32 po[4];
    qkchunk(c0 + 1, po);

    i32x8 a8 = {(int)pe[0], (int)pe[1], (int)pe[2], (int)pe[3],
                (int)po[0], (int)po[1], (int)po[2], (int)po[3]};
    const char* vd = smem + 16384 + (cp & 1) * 16384;
    __builtin_amdgcn_s_setprio(1);
#pragma unroll
    for (int dt = 0; dt < 8; ++dt) {
      uint4 v0 = *(const uint4*)(vd + dt * 2048 + l * 16);
      uint4 v1 = *(const uint4*)(vd + dt * 2048 + 1024 + l * 16);
      o[dt] = MFMAS(a8, mk8(v0, v1), o[dt]);
    }
    __builtin_amdgcn_s_setprio(0);
  }

  // epilogue: finalize lsum (other 16-kv half lives in lane^32), fp8 partial-O out
  lsum += __shfl_xor(lsum, 32);
  u8* pb = part + (size_t)sp * 4096 * 2048;
#pragma unroll
  for (int i = 0; i < 16; ++i) {
    const int r = (i & 3) + 8 * (i >> 2) + 4 * hi;
    const size_t qg = (size_t)(qb * 128 + w * 32 + r);
#pragma unroll
    for (int dt = 0; dt < 8; ++dt)
      pb[qg * 2048 + head * 256 + dt * 32 + q31] =
          (u8)(CVT8(o[dt][i], 0.0f, 0, false) & 0xff);
  }
  if (hi == 0) {
    const int qg = qb * 128 + w * 32 + q31;
    ml[(sp * 8 + head) * 4096 + qg] = lsum;
  }
}

// ---------------- launch ----------------
extern "C" void kernel_launch(void* const* d_in, const int* in_sizes, int n_in,
                              void* d_out, int out_size, void* d_ws, size_t ws_size,
                              hipStream_t stream) {
  const float* x   = (const float*)d_in[0];
  const float* Wq  = (const float*)d_in[1];
  const float* Wk  = (const float*)d_in[2];
  const float* Wv  = (const float*)d_in[3];
  const float* Wo  = (const float*)d_in[4];
  const float* bo  = (const float*)d_in[5];
  const float* g1  = (const float*)d_in[6];
  const float* be1 = (const float*)d_in[7];
  const float* g2  = (const float*)d_in[8];
  const float* be2 = (const float*)d_in[9];
  const float* W1  = (const float*)d_in[10];
  const float* b1  = (const float*)d_in[11];
  const float* W2  = (const float*)d_in[12];
  const float* b2  = (const float*)d_in[13];

  char* ws = (char*)d_ws;
  size_t off = 0;
  auto alloc = [&](size_t n) {
    char* p = ws + off;
    off = (off + n + 255) & ~(size_t)255;
    return p;
  };
  u8*  h8c   = (u8*)alloc(4096 * 256);
  u8*  Wq8   = (u8*)alloc(2048 * 256);
  u8*  Wk8   = (u8*)alloc(2048 * 256);
  u8*  Wv8   = (u8*)alloc(2048 * 256);
  u16* Wob   = (u16*)alloc(256 * 2048 * 2);
  u8*  W18   = (u8*)alloc(1024 * 256);
  u8*  W28   = (u8*)alloc(256 * 1024);
  u8*  Qb8   = (u8*)alloc((size_t)4096 * 2048);
  u8*  Kb8   = (u8*)alloc((size_t)4096 * 2048);
  u8*  Vb8   = (u8*)alloc((size_t)2048 * 4096);
  u8*  attnb = (u8*)alloc((size_t)2 * 4096 * 2048);
  float* mlb = (float*)alloc(16 * 4096 * 4);
  float* x2  = (float*)alloc(4096 * 256 * 4);
  u8*  h28   = (u8*)alloc(4096 * 256);
  u8*  ffn18 = (u8*)alloc((size_t)4096 * 1024);
  u16* pbuf  = (u16*)Qb8;

  k_prep<<<dim3(1024, 7), 256, 0, stream>>>(Wq, Wk, Wv, Wo, W1, W2,
                                            Wq8, Wk8, Wv8, Wob, W18, W28,
                                            x, g1, be1, h8c);

  k_gemm_qkv<<<dim3(48, 32), 256, 0, stream>>>(h8c, Wq8, Wk8, Wv8, Qb8, Kb8, Vb8);

  k_attn<<<dim3(8, 32, 2), 256, 0, stream>>>(Qb8, Kb8, Vb8, attnb, mlb);

  k_gemm_wo<<<dim3(2, 32, 4), 256, 0, stream>>>(attnb, mlb, Wob, pbuf);
  k_red4ln<<<1024, 256, 0, stream>>>(pbuf, bo, x, g2, be2, x2, h28);
  k_gemm_ffn1<<<dim3(8, 32), 256, 0, stream>>>(h28, W18, b1, ffn18);
  k_gemm_ffn2<<<dim3(2, 32, 4), 256, 0, stream>>>(ffn18, W28, pbuf);
  k_red4<<<1024, 256, 0, stream>>>(pbuf, b2, x2, (float*)d_out);
}